// Round 4
// baseline (472.860 us; speedup 1.0000x reference)
//
#include <hip/hip_runtime.h>
#include <hip/hip_bf16.h>

#define NUM_USER 50000
#define N_NODES  80000
#define DIM      64
#define NEG_SLOPE 0.01f

// bucket geometry: 256 rows per bucket
#define NB 313               // ceil(80000/256)
#define BSHIFT 8
#define RMASK 255
#define CSHIFT 17
#define CMASK 0x1FFFF

typedef __attribute__((ext_vector_type(8))) short short8;   // 8 bf16 = 4 VGPRs
typedef __attribute__((ext_vector_type(4))) float f32x4;    // MFMA 16x16 accumulator

typedef unsigned short XT;   // state dtype: bf16

__device__ __forceinline__ float leaky(float v) {
    return v > 0.0f ? v : v * NEG_SLOPE;
}

// flags[0]: edge_index is int64 (else int32)
// flags[1]: float inputs are bf16 (else fp32)
__device__ __forceinline__ int load_idx(const void* ei, int is64, long long pos) {
    if (is64) return (int)((const long long*)ei)[pos];
    return ((const int*)ei)[pos];
}
__device__ __forceinline__ float load_f(const void* p, int isbf16, size_t i) {
    if (isbf16) return __bfloat162float(((const __hip_bfloat16*)p)[i]);
    return ((const float*)p)[i];
}

__device__ __forceinline__ unsigned short f2bf(float f) {
    unsigned u = __float_as_uint(f);
    u += 0x7fffu + ((u >> 16) & 1u);   // RNE
    return (unsigned short)(u >> 16);
}

__device__ __forceinline__ void acc8(float* a, uint4 r) {
    a[0] += __uint_as_float(r.x << 16);
    a[1] += __uint_as_float(r.x & 0xffff0000u);
    a[2] += __uint_as_float(r.y << 16);
    a[3] += __uint_as_float(r.y & 0xffff0000u);
    a[4] += __uint_as_float(r.z << 16);
    a[5] += __uint_as_float(r.z & 0xffff0000u);
    a[6] += __uint_as_float(r.w << 16);
    a[7] += __uint_as_float(r.w & 0xffff0000u);
}

// ---------- detect (wave-parallel) + zero bucket counters ----------
__global__ void detect_kernel(const unsigned int* __restrict__ feat_words,
                              const int* __restrict__ ei_words,
                              int* __restrict__ flags,
                              int* __restrict__ bucketCnt) {
    int lane = threadIdx.x & 63;
    for (int i = lane; i < 320; i += 64) bucketCnt[i] = 0;
    int orv = 0;
    for (int i = lane * 2 + 1; i < 1024; i += 128) orv |= ei_words[i];
    int hits = 0;
    for (int i = lane; i < 256; i += 64) {
        unsigned e = (feat_words[i] >> 7) & 0xFF;
        hits += (e == 126 || e == 127) ? 1 : 0;
    }
    #pragma unroll
    for (int d = 32; d > 0; d >>= 1) {
        orv  |= __shfl_xor(orv, d, 64);
        hits += __shfl_xor(hits, d, 64);
    }
    if (lane == 0 && blockIdx.x == 0) {
        flags[0] = (orv == 0) ? 1 : 0;
        flags[1] = (hits > 64) ? 1 : 0;
    }
}

// ---------- fused: bucket count + init_x + W/b pack (three block ranges) ----------
__global__ __launch_bounds__(256) void countinit_kernel(
        const void* __restrict__ ei, int E, int cntBlocks, int initBlocks,
        const int* __restrict__ flags,
        int* __restrict__ bucketCnt,
        const void* __restrict__ vp, const void* __restrict__ tp,
        const void* __restrict__ vf, const void* __restrict__ tf,
        XT* __restrict__ xc,
        const void* __restrict__ vW, const void* __restrict__ tW,
        const void* __restrict__ vb, const void* __restrict__ tb,
        unsigned short* __restrict__ Wbf, float* __restrict__ bfp) {
    if ((int)blockIdx.x < cntBlocks) {
        __shared__ int bcnt[320];
        int tid = threadIdx.x;
        for (int i = tid; i < 320; i += 256) bcnt[i] = 0;
        __syncthreads();
        int is64 = flags[0];
        int base = blockIdx.x * 2048;
        #pragma unroll
        for (int it = 0; it < 8; ++it) {
            int e = base + it * 256 + tid;
            if (e < E) {
                int r = load_idx(ei, is64, e);
                int c = load_idx(ei, is64, (long long)E + e);
                if ((unsigned)r < N_NODES && (unsigned)c < N_NODES)
                    atomicAdd(&bcnt[r >> BSHIFT], 1);
            }
        }
        __syncthreads();
        for (int i = tid; i < NB; i += 256) {
            int v = bcnt[i];
            if (v) atomicAdd(&bucketCnt[i], v);
        }
    } else if ((int)blockIdx.x < cntBlocks + initBlocks) {
        int n = (blockIdx.x - cntBlocks) * 4 + (threadIdx.x >> 6);
        if (n >= N_NODES) return;
        int lane = threadIdx.x & 63;
        int isb = flags[1];
        float a, b;
        if (n < NUM_USER) {
            a = load_f(vp, isb, (size_t)n * DIM + lane);
            b = load_f(tp, isb, (size_t)n * DIM + lane);
        } else {
            a = load_f(vf, isb, (size_t)(n - NUM_USER) * DIM + lane);
            b = load_f(tf, isb, (size_t)(n - NUM_USER) * DIM + lane);
        }
        float sa = a * a, sb = b * b;
        #pragma unroll
        for (int d = 32; d > 0; d >>= 1) {
            sa += __shfl_xor(sa, d, 64);
            sb += __shfl_xor(sb, d, 64);
        }
        float ra = 1.0f / fmaxf(sqrtf(sa), 1e-12f);
        float rb = 1.0f / fmaxf(sqrtf(sb), 1e-12f);
        xc[(size_t)n * 128 + lane]      = f2bf(a * ra);
        xc[(size_t)n * 128 + 64 + lane] = f2bf(b * rb);
    } else {
        int isb = flags[1];
        int j = (blockIdx.x - cntBlocks - initBlocks) * 256 + threadIdx.x;
        if (j < 2 * 24576) {
            int tw = j / 24576, r = j % 24576;
            Wbf[j] = f2bf(load_f(tw ? tW : vW, isb, r));
        } else if (j < 2 * 24576 + 2 * 384) {
            int i2 = j - 2 * 24576;
            int tw = i2 / 384, r = i2 % 384;
            bfp[i2] = load_f(tw ? tb : vb, isb, r);
        }
    }
}

// ---------- scan 313 bucket counts -> bases + cursors (1 block) ----------
__global__ __launch_bounds__(512) void bucketscan_kernel(
        const int* __restrict__ bucketCnt,
        int* __restrict__ bucketBase, int* __restrict__ bucketCur) {
    __shared__ int sc[512];
    int t = threadIdx.x;
    int v = (t < NB) ? bucketCnt[t] : 0;
    sc[t] = v;
    __syncthreads();
    for (int d = 1; d < 512; d <<= 1) {
        int x = sc[t];
        int y = (t >= d) ? sc[t - d] : 0;
        __syncthreads();
        sc[t] = x + y;
        __syncthreads();
    }
    if (t < NB) {
        int excl = sc[t] - v;
        bucketBase[t] = excl;
        bucketCur[t]  = excl;
        if (t == NB - 1) bucketBase[NB] = sc[t];
    }
}

// ---------- binplace: edges -> per-bucket record arrays ----------
__global__ __launch_bounds__(320) void binplace_kernel(
        const void* __restrict__ ei, int E,
        const int* __restrict__ flags,
        int* __restrict__ bucketCur, unsigned int* __restrict__ recs) {
    __shared__ int bloc[320];
    __shared__ int bres[320];
    int tid = threadIdx.x;
    bloc[tid] = 0;
    __syncthreads();
    int is64 = flags[0];
    int base = blockIdx.x * 2560;

    int bb[8], cc[8], lp[8], rl[8];
    #pragma unroll
    for (int it = 0; it < 8; ++it) {
        bb[it] = -1;
        int e = base + it * 320 + tid;
        if (e < E) {
            int r = load_idx(ei, is64, e);
            int c = load_idx(ei, is64, (long long)E + e);
            if ((unsigned)r < N_NODES && (unsigned)c < N_NODES) {
                int b = r >> BSHIFT;
                bb[it] = b;
                cc[it] = c;
                rl[it] = r & RMASK;
                lp[it] = atomicAdd(&bloc[b], 1);
            }
        }
    }
    __syncthreads();
    if (tid < NB) {
        int v = bloc[tid];
        bres[tid] = v ? atomicAdd(&bucketCur[tid], v) : 0;
    }
    __syncthreads();
    #pragma unroll
    for (int it = 0; it < 8; ++it) {
        if (bb[it] >= 0) {
            int pos = bres[bb[it]] + lp[it];
            recs[pos] = ((unsigned)rl[it] << CSHIFT) | (unsigned)cc[it];
        }
    }
}

// ---------- bin2csr: one block per bucket (512 thr for edge phases) ----------
__global__ __launch_bounds__(512) void bin2csr_kernel(
        const unsigned int* __restrict__ recs,
        const int* __restrict__ bucketBase,
        int* __restrict__ cnt, int* __restrict__ cur,
        int* __restrict__ csr) {
    __shared__ int rcnt[256];
    __shared__ int sc[256];
    __shared__ int lcur[256];
    int b = blockIdx.x;
    int t = threadIdx.x;
    int base = bucketBase[b];
    int count = bucketBase[b + 1] - base;

    if (t < 256) { rcnt[t] = 0; lcur[t] = 0; }
    __syncthreads();
    for (int i = t; i < count; i += 512) {
        unsigned rec = recs[base + i];
        atomicAdd(&rcnt[rec >> CSHIFT], 1);
    }
    __syncthreads();
    int v = (t < 256) ? rcnt[t] : 0;
    if (t < 256) sc[t] = v;
    __syncthreads();
    for (int d = 1; d < 256; d <<= 1) {
        int x = 0;
        if (t < 256) { x = sc[t]; if (t >= d) x += sc[t - d]; }
        __syncthreads();
        if (t < 256) sc[t] = x;
        __syncthreads();
    }
    if (t < 256) {
        int row = (b << BSHIFT) + t;
        if (row < N_NODES) {
            cnt[row] = v;
            cur[row] = base + sc[t];   // row end; gather recovers start = cur - cnt
        }
    }
    __syncthreads();
    for (int i = t; i < count; i += 512) {
        unsigned rec = recs[base + i];
        int rloc = rec >> CSHIFT;
        int c = rec & CMASK;
        int pos = base + (sc[rloc] - rcnt[rloc]) + atomicAdd(&lcur[rloc], 1);
        csr[pos] = c;
    }
}

// ---------- fused gather + dense (MFMA 16x16x32 bf16) ----------
// Gather computed in-register, per-lane layout == MFMA A-fragment layout:
// lane (l16, quad) owns node n0+l16, cols [quad*8, quad*8+8) and
// [32+quad*8, 32+quad*8+8) of its tower's half. A 4-lane team (same l16)
// covers the 64-col half; accumulate serially over all d neighbors -> no
// shuffle reduce, no agg buffer. xin/xout ping-pong kills the RAW race.
__global__ __launch_bounds__(256) void dense_fused_kernel(
        const XT* __restrict__ xin, XT* __restrict__ xout,
        const void* __restrict__ id_emb,
        const unsigned short* __restrict__ Wbf, const float* __restrict__ bfp,
        const int* __restrict__ cnt, const int* __restrict__ cur,
        const int* __restrict__ csr,
        int layer, const int* __restrict__ flags) {
    __shared__ unsigned short hts[4][16 * 72];
    int wave = threadIdx.x >> 6, lane = threadIdx.x & 63;
    int quad = lane >> 4, l16 = lane & 15;
    int tower = blockIdx.y;
    int isb = flags[1];
    int n0 = (blockIdx.x * 4 + wave) * 16;
    int toff = tower * 64;
    const unsigned short* Wm = Wbf + (size_t)((tower * 2 + layer) * 3) * 4096;
    const float* bb = bfp + (tower * 2 + layer) * 192;
    unsigned short* ht = hts[wave];

    // ---- in-register gather (mean of neighbor rows, this lane's 16 cols)
    int node = n0 + l16;
    int d = cnt[node];
    int base = cur[node] - d;
    const int* nb = csr + base;
    const XT* xt = xin + toff + quad * 8;

    float g0[8], g1[8];
    #pragma unroll
    for (int f = 0; f < 8; ++f) { g0[f] = 0.f; g1[f] = 0.f; }

    int jj = 0;
    for (; jj + 1 < d; jj += 2) {
        int c0 = nb[jj];
        int c1 = nb[jj + 1];
        const XT* p0 = xt + (size_t)c0 * 128;
        const XT* p1 = xt + (size_t)c1 * 128;
        uint4 u0 = *(const uint4*)(p0);
        uint4 w0 = *(const uint4*)(p0 + 32);
        uint4 u1 = *(const uint4*)(p1);
        uint4 w1 = *(const uint4*)(p1 + 32);
        acc8(g0, u0); acc8(g1, w0);
        acc8(g0, u1); acc8(g1, w1);
    }
    if (jj < d) {
        int c0 = nb[jj];
        const XT* p0 = xt + (size_t)c0 * 128;
        uint4 u0 = *(const uint4*)(p0);
        uint4 w0 = *(const uint4*)(p0 + 32);
        acc8(g0, u0); acc8(g1, w0);
    }
    float invd = (d > 0) ? 1.0f / (float)d : 0.0f;
    short8 ga0, ga1;
    #pragma unroll
    for (int f = 0; f < 8; ++f) {
        ga0[f] = (short)f2bf(g0[f] * invd);
        ga1[f] = (short)f2bf(g1[f] * invd);
    }

    size_t arow = (size_t)(n0 + l16) * 128 + toff + quad * 8;

    short8 a0, a1;
    f32x4 accP[4];

    // M1: P = leaky(x @ W1^T + b1), in registers
    a0 = *(const short8*)(xin + arow);
    a1 = *(const short8*)(xin + arow + 32);
    #pragma unroll
    for (int t = 0; t < 4; ++t) {
        f32x4 c = {0.f, 0.f, 0.f, 0.f};
        short8 b0 = *(const short8*)(Wm + 4096 + (16 * t + l16) * 64 + quad * 8);
        short8 b1 = *(const short8*)(Wm + 4096 + (16 * t + l16) * 64 + 32 + quad * 8);
        c = __builtin_amdgcn_mfma_f32_16x16x32_bf16(a0, b0, c, 0, 0, 0);
        c = __builtin_amdgcn_mfma_f32_16x16x32_bf16(a1, b1, c, 0, 0, 0);
        float bias = bb[64 + 16 * t + l16];
        #pragma unroll
        for (int r = 0; r < 4; ++r) accP[t][r] = leaky(c[r] + bias);
    }

    // M0: h = leaky(gathered_mean @ W0^T + b0) -> LDS (C-layout -> A-layout)
    #pragma unroll
    for (int t = 0; t < 4; ++t) {
        f32x4 c = {0.f, 0.f, 0.f, 0.f};
        short8 b0 = *(const short8*)(Wm + (16 * t + l16) * 64 + quad * 8);
        short8 b1 = *(const short8*)(Wm + (16 * t + l16) * 64 + 32 + quad * 8);
        c = __builtin_amdgcn_mfma_f32_16x16x32_bf16(ga0, b0, c, 0, 0, 0);
        c = __builtin_amdgcn_mfma_f32_16x16x32_bf16(ga1, b1, c, 0, 0, 0);
        float bias = bb[16 * t + l16];
        #pragma unroll
        for (int r = 0; r < 4; ++r)
            ht[(quad * 4 + r) * 72 + 16 * t + l16] = f2bf(leaky(c[r] + bias));
    }
    // wave-private LDS, in-order per wave -> no barrier

    // M2: x = leaky(h @ W2^T + b2 + P + id)
    a0 = *(const short8*)(ht + l16 * 72 + quad * 8);
    a1 = *(const short8*)(ht + l16 * 72 + 32 + quad * 8);
    #pragma unroll
    for (int t = 0; t < 4; ++t) {
        f32x4 c = {0.f, 0.f, 0.f, 0.f};
        short8 b0 = *(const short8*)(Wm + 2 * 4096 + (16 * t + l16) * 64 + quad * 8);
        short8 b1 = *(const short8*)(Wm + 2 * 4096 + (16 * t + l16) * 64 + 32 + quad * 8);
        c = __builtin_amdgcn_mfma_f32_16x16x32_bf16(a0, b0, c, 0, 0, 0);
        c = __builtin_amdgcn_mfma_f32_16x16x32_bf16(a1, b1, c, 0, 0, 0);
        float bias = bb[128 + 16 * t + l16];
        #pragma unroll
        for (int r = 0; r < 4; ++r) {
            int node2 = n0 + quad * 4 + r;
            int j = 16 * t + l16;
            float idv = load_f(id_emb, isb, (size_t)node2 * 64 + j);
            xout[(size_t)node2 * 128 + toff + j] = f2bf(leaky(c[r] + bias + accP[t][r] + idv));
        }
    }
}

// ---------- out = (rep_v + rep_t)/2, 8 values/thread ----------
__global__ void final_kernel(const XT* __restrict__ xc, void* __restrict__ out,
                             const int* __restrict__ flags, int n8) {
    int i = blockIdx.x * blockDim.x + threadIdx.x;
    if (i >= n8) return;
    int n = i >> 3, s = i & 7;
    uint4 v = ((const uint4*)(xc + (size_t)n * 128))[s];
    uint4 t = ((const uint4*)(xc + (size_t)n * 128 + 64))[s];
    float r[8];
    r[0] = (__uint_as_float(v.x << 16) + __uint_as_float(t.x << 16)) * 0.5f;
    r[1] = (__uint_as_float(v.x & 0xffff0000u) + __uint_as_float(t.x & 0xffff0000u)) * 0.5f;
    r[2] = (__uint_as_float(v.y << 16) + __uint_as_float(t.y << 16)) * 0.5f;
    r[3] = (__uint_as_float(v.y & 0xffff0000u) + __uint_as_float(t.y & 0xffff0000u)) * 0.5f;
    r[4] = (__uint_as_float(v.z << 16) + __uint_as_float(t.z << 16)) * 0.5f;
    r[5] = (__uint_as_float(v.z & 0xffff0000u) + __uint_as_float(t.z & 0xffff0000u)) * 0.5f;
    r[6] = (__uint_as_float(v.w << 16) + __uint_as_float(t.w << 16)) * 0.5f;
    r[7] = (__uint_as_float(v.w & 0xffff0000u) + __uint_as_float(t.w & 0xffff0000u)) * 0.5f;
    if (flags[1]) {
        uint4 o;
        o.x = (unsigned)f2bf(r[0]) | ((unsigned)f2bf(r[1]) << 16);
        o.y = (unsigned)f2bf(r[2]) | ((unsigned)f2bf(r[3]) << 16);
        o.z = (unsigned)f2bf(r[4]) | ((unsigned)f2bf(r[5]) << 16);
        o.w = (unsigned)f2bf(r[6]) | ((unsigned)f2bf(r[7]) << 16);
        ((uint4*)out)[i] = o;
    } else {
        float4* o = (float4*)out;
        o[i * 2 + 0] = make_float4(r[0], r[1], r[2], r[3]);
        o[i * 2 + 1] = make_float4(r[4], r[5], r[6], r[7]);
    }
}

extern "C" void kernel_launch(void* const* d_in, const int* in_sizes, int n_in,
                              void* d_out, int out_size, void* d_ws, size_t ws_size,
                              hipStream_t stream) {
    const void* v_feat = d_in[0];
    const void* t_feat = d_in[1];
    const void* id_emb = d_in[2];
    const void* v_pref = d_in[3];
    const void* t_pref = d_in[4];
    const void* v_W    = d_in[5];
    const void* v_b    = d_in[6];
    const void* t_W    = d_in[7];
    const void* t_b    = d_in[8];
    const void* ei     = d_in[9];

    const int E = in_sizes[9] / 2;   // 1,600,000
    char* ws = (char*)d_ws;

    size_t o = 0;
    int*            flags     = (int*)(ws + o);            o += 16;
    int*            cnt       = (int*)(ws + o);            o += 320000;
    int*            cur       = (int*)(ws + o);            o += 320000;
    int*            bucketCnt = (int*)(ws + o);            o += 320 * 4;
    int*            bucketBase= (int*)(ws + o);            o += 320 * 4;
    int*            bucketCur = (int*)(ws + o);            o += 320 * 4;
    unsigned short* Wbf       = (unsigned short*)(ws + o); o += 2 * 24576 * 2;
    float*          bfp       = (float*)(ws + o);          o += 2 * 384 * 4;
    XT* xcA = (XT*)(ws + o); o += (size_t)N_NODES * 128 * sizeof(XT);
    XT* xcB = (XT*)(ws + o); o += (size_t)N_NODES * 128 * sizeof(XT);
    unsigned int* recs = (unsigned int*)(ws + o); o += (size_t)E * 4;
    int* csr = (int*)(ws + o);                    // tight: E*4 = 6.4 MB

    detect_kernel<<<dim3(1), dim3(64), 0, stream>>>(
        (const unsigned int*)v_feat, (const int*)ei, flags, bucketCnt);

    // fused bucket count + init_x + W/b pack
    const int cntBlocks  = (E + 2047) / 2048;         // 782
    const int initBlocks = (N_NODES + 3) / 4;         // 20000
    const int packBlocks = (2 * 24576 + 2 * 384 + 255) / 256;  // 198
    countinit_kernel<<<dim3(cntBlocks + initBlocks + packBlocks), dim3(256), 0, stream>>>(
        ei, E, cntBlocks, initBlocks, flags, bucketCnt,
        v_pref, t_pref, v_feat, t_feat, xcA,
        v_W, t_W, v_b, t_b, Wbf, bfp);

    // scan 313 bucket counts
    bucketscan_kernel<<<dim3(1), dim3(512), 0, stream>>>(bucketCnt, bucketBase, bucketCur);

    // edges -> bucketed records
    binplace_kernel<<<dim3((E + 2559) / 2560), dim3(320), 0, stream>>>(
        ei, E, flags, bucketCur, recs);

    // buckets -> tight CSR + per-row cnt/cur
    bin2csr_kernel<<<dim3(NB), dim3(512), 0, stream>>>(recs, bucketBase, cnt, cur, csr);

    const int denseBlocks = N_NODES / (16 * 4);       // 1250, exact

    // layer 0: xcA -> xcB ; layer 1: xcB -> xcA
    dense_fused_kernel<<<dim3(denseBlocks, 2), dim3(256), 0, stream>>>(
        xcA, xcB, id_emb, Wbf, bfp, cnt, cur, csr, 0, flags);
    dense_fused_kernel<<<dim3(denseBlocks, 2), dim3(256), 0, stream>>>(
        xcB, xcA, id_emb, Wbf, bfp, cnt, cur, csr, 1, flags);

    const int n8 = N_NODES * DIM / 8;                 // 640000
    final_kernel<<<dim3((n8 + 255) / 256), dim3(256), 0, stream>>>(xcA, d_out, flags, n8);
}

// Round 5
// 421.584 us; speedup vs baseline: 1.1216x; 1.1216x over previous
//
#include <hip/hip_runtime.h>
#include <hip/hip_bf16.h>

#define NUM_USER 50000
#define N_NODES  80000
#define DIM      64
#define NEG_SLOPE 0.01f

// bucket geometry: 256 rows per bucket
#define NB 313               // ceil(80000/256)
#define BSHIFT 8
#define RMASK 255
#define CSHIFT 17
#define CMASK 0x1FFFF

typedef __attribute__((ext_vector_type(8))) short short8;   // 8 bf16 = 4 VGPRs
typedef __attribute__((ext_vector_type(4))) float f32x4;    // MFMA 16x16 accumulator

typedef unsigned short XT;   // state dtype: bf16

__device__ __forceinline__ float leaky(float v) {
    return v > 0.0f ? v : v * NEG_SLOPE;
}

// flags[0]: edge_index is int64 (else int32)
// flags[1]: float inputs are bf16 (else fp32)
__device__ __forceinline__ int load_idx(const void* ei, int is64, long long pos) {
    if (is64) return (int)((const long long*)ei)[pos];
    return ((const int*)ei)[pos];
}
__device__ __forceinline__ float load_f(const void* p, int isbf16, size_t i) {
    if (isbf16) return __bfloat162float(((const __hip_bfloat16*)p)[i]);
    return ((const float*)p)[i];
}

__device__ __forceinline__ unsigned short f2bf(float f) {
    unsigned u = __float_as_uint(f);
    u += 0x7fffu + ((u >> 16) & 1u);   // RNE
    return (unsigned short)(u >> 16);
}

__device__ __forceinline__ void acc8(float* a, uint4 r) {
    a[0] += __uint_as_float(r.x << 16);
    a[1] += __uint_as_float(r.x & 0xffff0000u);
    a[2] += __uint_as_float(r.y << 16);
    a[3] += __uint_as_float(r.y & 0xffff0000u);
    a[4] += __uint_as_float(r.z << 16);
    a[5] += __uint_as_float(r.z & 0xffff0000u);
    a[6] += __uint_as_float(r.w << 16);
    a[7] += __uint_as_float(r.w & 0xffff0000u);
}

// ---------- detect (wave-parallel) + zero bucket counters ----------
__global__ void detect_kernel(const unsigned int* __restrict__ feat_words,
                              const int* __restrict__ ei_words,
                              int* __restrict__ flags,
                              int* __restrict__ bucketCnt) {
    int lane = threadIdx.x & 63;
    for (int i = lane; i < 320; i += 64) bucketCnt[i] = 0;
    int orv = 0;
    for (int i = lane * 2 + 1; i < 1024; i += 128) orv |= ei_words[i];
    int hits = 0;
    for (int i = lane; i < 256; i += 64) {
        unsigned e = (feat_words[i] >> 7) & 0xFF;
        hits += (e == 126 || e == 127) ? 1 : 0;
    }
    #pragma unroll
    for (int d = 32; d > 0; d >>= 1) {
        orv  |= __shfl_xor(orv, d, 64);
        hits += __shfl_xor(hits, d, 64);
    }
    if (lane == 0 && blockIdx.x == 0) {
        flags[0] = (orv == 0) ? 1 : 0;
        flags[1] = (hits > 64) ? 1 : 0;
    }
}

// ---------- fused: bucket count + init_x + W/b pack (three block ranges) ----------
__global__ __launch_bounds__(256) void countinit_kernel(
        const void* __restrict__ ei, int E, int cntBlocks, int initBlocks,
        const int* __restrict__ flags,
        int* __restrict__ bucketCnt,
        const void* __restrict__ vp, const void* __restrict__ tp,
        const void* __restrict__ vf, const void* __restrict__ tf,
        XT* __restrict__ xc,
        const void* __restrict__ vW, const void* __restrict__ tW,
        const void* __restrict__ vb, const void* __restrict__ tb,
        unsigned short* __restrict__ Wbf, float* __restrict__ bfp) {
    if ((int)blockIdx.x < cntBlocks) {
        __shared__ int bcnt[320];
        int tid = threadIdx.x;
        for (int i = tid; i < 320; i += 256) bcnt[i] = 0;
        __syncthreads();
        int is64 = flags[0];
        int base = blockIdx.x * 2048;
        #pragma unroll
        for (int it = 0; it < 8; ++it) {
            int e = base + it * 256 + tid;
            if (e < E) {
                int r = load_idx(ei, is64, e);
                int c = load_idx(ei, is64, (long long)E + e);
                if ((unsigned)r < N_NODES && (unsigned)c < N_NODES)
                    atomicAdd(&bcnt[r >> BSHIFT], 1);
            }
        }
        __syncthreads();
        for (int i = tid; i < NB; i += 256) {
            int v = bcnt[i];
            if (v) atomicAdd(&bucketCnt[i], v);
        }
    } else if ((int)blockIdx.x < cntBlocks + initBlocks) {
        int n = (blockIdx.x - cntBlocks) * 4 + (threadIdx.x >> 6);
        if (n >= N_NODES) return;
        int lane = threadIdx.x & 63;
        int isb = flags[1];
        float a, b;
        if (n < NUM_USER) {
            a = load_f(vp, isb, (size_t)n * DIM + lane);
            b = load_f(tp, isb, (size_t)n * DIM + lane);
        } else {
            a = load_f(vf, isb, (size_t)(n - NUM_USER) * DIM + lane);
            b = load_f(tf, isb, (size_t)(n - NUM_USER) * DIM + lane);
        }
        float sa = a * a, sb = b * b;
        #pragma unroll
        for (int d = 32; d > 0; d >>= 1) {
            sa += __shfl_xor(sa, d, 64);
            sb += __shfl_xor(sb, d, 64);
        }
        float ra = 1.0f / fmaxf(sqrtf(sa), 1e-12f);
        float rb = 1.0f / fmaxf(sqrtf(sb), 1e-12f);
        xc[(size_t)n * 128 + lane]      = f2bf(a * ra);
        xc[(size_t)n * 128 + 64 + lane] = f2bf(b * rb);
    } else {
        int isb = flags[1];
        int j = (blockIdx.x - cntBlocks - initBlocks) * 256 + threadIdx.x;
        if (j < 2 * 24576) {
            int tw = j / 24576, r = j % 24576;
            Wbf[j] = f2bf(load_f(tw ? tW : vW, isb, r));
        } else if (j < 2 * 24576 + 2 * 384) {
            int i2 = j - 2 * 24576;
            int tw = i2 / 384, r = i2 % 384;
            bfp[i2] = load_f(tw ? tb : vb, isb, r);
        }
    }
}

// ---------- scan 313 bucket counts -> bases + cursors (1 block) ----------
__global__ __launch_bounds__(512) void bucketscan_kernel(
        const int* __restrict__ bucketCnt,
        int* __restrict__ bucketBase, int* __restrict__ bucketCur) {
    __shared__ int sc[512];
    int t = threadIdx.x;
    int v = (t < NB) ? bucketCnt[t] : 0;
    sc[t] = v;
    __syncthreads();
    for (int d = 1; d < 512; d <<= 1) {
        int x = sc[t];
        int y = (t >= d) ? sc[t - d] : 0;
        __syncthreads();
        sc[t] = x + y;
        __syncthreads();
    }
    if (t < NB) {
        int excl = sc[t] - v;
        bucketBase[t] = excl;
        bucketCur[t]  = excl;
        if (t == NB - 1) bucketBase[NB] = sc[t];
    }
}

// ---------- binplace: edges -> per-bucket record arrays ----------
__global__ __launch_bounds__(320) void binplace_kernel(
        const void* __restrict__ ei, int E,
        const int* __restrict__ flags,
        int* __restrict__ bucketCur, unsigned int* __restrict__ recs) {
    __shared__ int bloc[320];
    __shared__ int bres[320];
    int tid = threadIdx.x;
    bloc[tid] = 0;
    __syncthreads();
    int is64 = flags[0];
    int base = blockIdx.x * 2560;

    int bb[8], cc[8], lp[8], rl[8];
    #pragma unroll
    for (int it = 0; it < 8; ++it) {
        bb[it] = -1;
        int e = base + it * 320 + tid;
        if (e < E) {
            int r = load_idx(ei, is64, e);
            int c = load_idx(ei, is64, (long long)E + e);
            if ((unsigned)r < N_NODES && (unsigned)c < N_NODES) {
                int b = r >> BSHIFT;
                bb[it] = b;
                cc[it] = c;
                rl[it] = r & RMASK;
                lp[it] = atomicAdd(&bloc[b], 1);
            }
        }
    }
    __syncthreads();
    if (tid < NB) {
        int v = bloc[tid];
        bres[tid] = v ? atomicAdd(&bucketCur[tid], v) : 0;
    }
    __syncthreads();
    #pragma unroll
    for (int it = 0; it < 8; ++it) {
        if (bb[it] >= 0) {
            int pos = bres[bb[it]] + lp[it];
            recs[pos] = ((unsigned)rl[it] << CSHIFT) | (unsigned)cc[it];
        }
    }
}

// ---------- bin2csr: one block per bucket (512 thr for edge phases) ----------
__global__ __launch_bounds__(512) void bin2csr_kernel(
        const unsigned int* __restrict__ recs,
        const int* __restrict__ bucketBase,
        int* __restrict__ cnt, int* __restrict__ cur,
        int* __restrict__ csr) {
    __shared__ int rcnt[256];
    __shared__ int sc[256];
    __shared__ int lcur[256];
    int b = blockIdx.x;
    int t = threadIdx.x;
    int base = bucketBase[b];
    int count = bucketBase[b + 1] - base;

    if (t < 256) { rcnt[t] = 0; lcur[t] = 0; }
    __syncthreads();
    for (int i = t; i < count; i += 512) {
        unsigned rec = recs[base + i];
        atomicAdd(&rcnt[rec >> CSHIFT], 1);
    }
    __syncthreads();
    int v = (t < 256) ? rcnt[t] : 0;
    if (t < 256) sc[t] = v;
    __syncthreads();
    for (int d = 1; d < 256; d <<= 1) {
        int x = 0;
        if (t < 256) { x = sc[t]; if (t >= d) x += sc[t - d]; }
        __syncthreads();
        if (t < 256) sc[t] = x;
        __syncthreads();
    }
    if (t < 256) {
        int row = (b << BSHIFT) + t;
        if (row < N_NODES) {
            cnt[row] = v;
            cur[row] = base + sc[t];   // row end; gather recovers start = cur - cnt
        }
    }
    __syncthreads();
    for (int i = t; i < count; i += 512) {
        unsigned rec = recs[base + i];
        int rloc = rec >> CSHIFT;
        int c = rec & CMASK;
        int pos = base + (sc[rloc] - rcnt[rloc]) + atomicAdd(&lcur[rloc], 1);
        csr[pos] = c;
    }
}

// ---------- gather: agg[n] = mean over tight-CSR neighbors ----------
// 8 streams/wave: 8 lanes cover a 128B half-row (uint4/lane); group g8 = gg*2+h
// handles neighbors jj = gg (mod 4), half h. Unroll-4 -> up to 32 outstanding
// row loads per wave (latency/MLP-bound; FETCH is compulsory per-XCD).
__global__ __launch_bounds__(512) void gather_kernel(
        const XT* __restrict__ xc, XT* __restrict__ agg,
        const int* __restrict__ cnt, const int* __restrict__ cur,
        const int* __restrict__ csr) {
    int n = blockIdx.x * 8 + (threadIdx.x >> 6);
    if (n >= N_NODES) return;
    int lane = threadIdx.x & 63;
    int g8 = lane >> 3;      // 0..7
    int s  = lane & 7;       // 0..7
    int gg = g8 >> 1;        // 0..3: neighbor stride class
    int h  = g8 & 1;         // 0/1: row half

    int d = cnt[n];
    int base = cur[n] - d;   // row start in tight CSR
    const int* nb = csr + base;
    const XT* xh = xc + h * 64;

    float acc[8];
    #pragma unroll
    for (int f = 0; f < 8; ++f) acc[f] = 0.f;

    int jj = gg;
    for (; jj + 12 < d; jj += 16) {
        int c0 = nb[jj];
        int c1 = nb[jj + 4];
        int c2 = nb[jj + 8];
        int c3 = nb[jj + 12];
        uint4 r0 = ((const uint4*)(xh + (size_t)c0 * 128))[s];
        uint4 r1 = ((const uint4*)(xh + (size_t)c1 * 128))[s];
        uint4 r2 = ((const uint4*)(xh + (size_t)c2 * 128))[s];
        uint4 r3 = ((const uint4*)(xh + (size_t)c3 * 128))[s];
        acc8(acc, r0);
        acc8(acc, r1);
        acc8(acc, r2);
        acc8(acc, r3);
    }
    for (; jj < d; jj += 4) {
        int c0 = nb[jj];
        uint4 r0 = ((const uint4*)(xh + (size_t)c0 * 128))[s];
        acc8(acc, r0);
    }

    // reduce across gg (lanes differing in bits 4 and 5; same h,s)
    #pragma unroll
    for (int dd = 16; dd < 64; dd <<= 1) {
        #pragma unroll
        for (int f = 0; f < 8; ++f) acc[f] += __shfl_xor(acc[f], dd, 64);
    }

    float invd = (d > 0) ? 1.0f / (float)d : 0.0f;
    if (g8 < 2) {   // gg == 0 lanes; h = g8 selects the half to write
        uint4 w;
        w.x = (unsigned)f2bf(acc[0] * invd) | ((unsigned)f2bf(acc[1] * invd) << 16);
        w.y = (unsigned)f2bf(acc[2] * invd) | ((unsigned)f2bf(acc[3] * invd) << 16);
        w.z = (unsigned)f2bf(acc[4] * invd) | ((unsigned)f2bf(acc[5] * invd) << 16);
        w.w = (unsigned)f2bf(acc[6] * invd) | ((unsigned)f2bf(acc[7] * invd) << 16);
        ((uint4*)(agg + (size_t)n * 128 + h * 64))[s] = w;
    }
}

// ---------- dense via MFMA 16x16x32 bf16 (verified R7) ----------
__global__ __launch_bounds__(256) void dense_mfma_kernel(
        XT* __restrict__ xc, const XT* __restrict__ agg,
        const void* __restrict__ id_emb,
        const unsigned short* __restrict__ Wbf, const float* __restrict__ bfp,
        int layer, const int* __restrict__ flags) {
    __shared__ unsigned short hts[4][16 * 72];
    int wave = threadIdx.x >> 6, lane = threadIdx.x & 63;
    int quad = lane >> 4, l16 = lane & 15;
    int tower = blockIdx.y;
    int isb = flags[1];
    int n0 = (blockIdx.x * 4 + wave) * 16;
    int toff = tower * 64;
    const unsigned short* Wm = Wbf + (size_t)((tower * 2 + layer) * 3) * 4096;
    const float* bb = bfp + (tower * 2 + layer) * 192;
    unsigned short* ht = hts[wave];

    size_t arow = (size_t)(n0 + l16) * 128 + toff + quad * 8;

    short8 a0, a1;
    f32x4 accP[4];

    // M1: P = leaky(x @ W1^T + b1), in registers
    a0 = *(const short8*)(xc + arow);
    a1 = *(const short8*)(xc + arow + 32);
    #pragma unroll
    for (int t = 0; t < 4; ++t) {
        f32x4 c = {0.f, 0.f, 0.f, 0.f};
        short8 b0 = *(const short8*)(Wm + 4096 + (16 * t + l16) * 64 + quad * 8);
        short8 b1 = *(const short8*)(Wm + 4096 + (16 * t + l16) * 64 + 32 + quad * 8);
        c = __builtin_amdgcn_mfma_f32_16x16x32_bf16(a0, b0, c, 0, 0, 0);
        c = __builtin_amdgcn_mfma_f32_16x16x32_bf16(a1, b1, c, 0, 0, 0);
        float bias = bb[64 + 16 * t + l16];
        #pragma unroll
        for (int r = 0; r < 4; ++r) accP[t][r] = leaky(c[r] + bias);
    }

    // M0: h = leaky(agg @ W0^T + b0) -> LDS (C-layout -> A-layout)
    a0 = *(const short8*)(agg + arow);
    a1 = *(const short8*)(agg + arow + 32);
    #pragma unroll
    for (int t = 0; t < 4; ++t) {
        f32x4 c = {0.f, 0.f, 0.f, 0.f};
        short8 b0 = *(const short8*)(Wm + (16 * t + l16) * 64 + quad * 8);
        short8 b1 = *(const short8*)(Wm + (16 * t + l16) * 64 + 32 + quad * 8);
        c = __builtin_amdgcn_mfma_f32_16x16x32_bf16(a0, b0, c, 0, 0, 0);
        c = __builtin_amdgcn_mfma_f32_16x16x32_bf16(a1, b1, c, 0, 0, 0);
        float bias = bb[16 * t + l16];
        #pragma unroll
        for (int r = 0; r < 4; ++r)
            ht[(quad * 4 + r) * 72 + 16 * t + l16] = f2bf(leaky(c[r] + bias));
    }
    // wave-private LDS, in-order per wave -> no barrier

    // M2: x = leaky(h @ W2^T + b2 + P + id)
    a0 = *(const short8*)(ht + l16 * 72 + quad * 8);
    a1 = *(const short8*)(ht + l16 * 72 + 32 + quad * 8);
    #pragma unroll
    for (int t = 0; t < 4; ++t) {
        f32x4 c = {0.f, 0.f, 0.f, 0.f};
        short8 b0 = *(const short8*)(Wm + 2 * 4096 + (16 * t + l16) * 64 + quad * 8);
        short8 b1 = *(const short8*)(Wm + 2 * 4096 + (16 * t + l16) * 64 + 32 + quad * 8);
        c = __builtin_amdgcn_mfma_f32_16x16x32_bf16(a0, b0, c, 0, 0, 0);
        c = __builtin_amdgcn_mfma_f32_16x16x32_bf16(a1, b1, c, 0, 0, 0);
        float bias = bb[128 + 16 * t + l16];
        #pragma unroll
        for (int r = 0; r < 4; ++r) {
            int node = n0 + quad * 4 + r;
            int j = 16 * t + l16;
            float idv = load_f(id_emb, isb, (size_t)node * 64 + j);
            xc[(size_t)node * 128 + toff + j] = f2bf(leaky(c[r] + bias + accP[t][r] + idv));
        }
    }
}

// ---------- out = (rep_v + rep_t)/2, 8 values/thread ----------
__global__ void final_kernel(const XT* __restrict__ xc, void* __restrict__ out,
                             const int* __restrict__ flags, int n8) {
    int i = blockIdx.x * blockDim.x + threadIdx.x;
    if (i >= n8) return;
    int n = i >> 3, s = i & 7;
    uint4 v = ((const uint4*)(xc + (size_t)n * 128))[s];
    uint4 t = ((const uint4*)(xc + (size_t)n * 128 + 64))[s];
    float r[8];
    r[0] = (__uint_as_float(v.x << 16) + __uint_as_float(t.x << 16)) * 0.5f;
    r[1] = (__uint_as_float(v.x & 0xffff0000u) + __uint_as_float(t.x & 0xffff0000u)) * 0.5f;
    r[2] = (__uint_as_float(v.y << 16) + __uint_as_float(t.y << 16)) * 0.5f;
    r[3] = (__uint_as_float(v.y & 0xffff0000u) + __uint_as_float(t.y & 0xffff0000u)) * 0.5f;
    r[4] = (__uint_as_float(v.z << 16) + __uint_as_float(t.z << 16)) * 0.5f;
    r[5] = (__uint_as_float(v.z & 0xffff0000u) + __uint_as_float(t.z & 0xffff0000u)) * 0.5f;
    r[6] = (__uint_as_float(v.w << 16) + __uint_as_float(t.w << 16)) * 0.5f;
    r[7] = (__uint_as_float(v.w & 0xffff0000u) + __uint_as_float(t.w & 0xffff0000u)) * 0.5f;
    if (flags[1]) {
        uint4 o;
        o.x = (unsigned)f2bf(r[0]) | ((unsigned)f2bf(r[1]) << 16);
        o.y = (unsigned)f2bf(r[2]) | ((unsigned)f2bf(r[3]) << 16);
        o.z = (unsigned)f2bf(r[4]) | ((unsigned)f2bf(r[5]) << 16);
        o.w = (unsigned)f2bf(r[6]) | ((unsigned)f2bf(r[7]) << 16);
        ((uint4*)out)[i] = o;
    } else {
        float4* o = (float4*)out;
        o[i * 2 + 0] = make_float4(r[0], r[1], r[2], r[3]);
        o[i * 2 + 1] = make_float4(r[4], r[5], r[6], r[7]);
    }
}

extern "C" void kernel_launch(void* const* d_in, const int* in_sizes, int n_in,
                              void* d_out, int out_size, void* d_ws, size_t ws_size,
                              hipStream_t stream) {
    const void* v_feat = d_in[0];
    const void* t_feat = d_in[1];
    const void* id_emb = d_in[2];
    const void* v_pref = d_in[3];
    const void* t_pref = d_in[4];
    const void* v_W    = d_in[5];
    const void* v_b    = d_in[6];
    const void* t_W    = d_in[7];
    const void* t_b    = d_in[8];
    const void* ei     = d_in[9];

    const int E = in_sizes[9] / 2;   // 1,600,000
    char* ws = (char*)d_ws;

    size_t o = 0;
    int*            flags     = (int*)(ws + o);            o += 16;
    int*            cnt       = (int*)(ws + o);            o += 320000;
    int*            cur       = (int*)(ws + o);            o += 320000;
    int*            bucketCnt = (int*)(ws + o);            o += 320 * 4;
    int*            bucketBase= (int*)(ws + o);            o += 320 * 4;
    int*            bucketCur = (int*)(ws + o);            o += 320 * 4;
    unsigned short* Wbf       = (unsigned short*)(ws + o); o += 2 * 24576 * 2;
    float*          bfp       = (float*)(ws + o);          o += 2 * 384 * 4;
    XT* xc  = (XT*)(ws + o); o += (size_t)N_NODES * 128 * sizeof(XT);
    XT* agg = (XT*)(ws + o); o += (size_t)N_NODES * 128 * sizeof(XT);
    unsigned int* recs = (unsigned int*)(ws + o); o += (size_t)E * 4;
    int* csr = (int*)(ws + o);                    // tight: E*4 = 6.4 MB

    detect_kernel<<<dim3(1), dim3(64), 0, stream>>>(
        (const unsigned int*)v_feat, (const int*)ei, flags, bucketCnt);

    // fused bucket count + init_x + W/b pack
    const int cntBlocks  = (E + 2047) / 2048;         // 782
    const int initBlocks = (N_NODES + 3) / 4;         // 20000
    const int packBlocks = (2 * 24576 + 2 * 384 + 255) / 256;
    countinit_kernel<<<dim3(cntBlocks + initBlocks + packBlocks), dim3(256), 0, stream>>>(
        ei, E, cntBlocks, initBlocks, flags, bucketCnt,
        v_pref, t_pref, v_feat, t_feat, xc,
        v_W, t_W, v_b, t_b, Wbf, bfp);

    // scan 313 bucket counts
    bucketscan_kernel<<<dim3(1), dim3(512), 0, stream>>>(bucketCnt, bucketBase, bucketCur);

    // edges -> bucketed records
    binplace_kernel<<<dim3((E + 2559) / 2560), dim3(320), 0, stream>>>(
        ei, E, flags, bucketCur, recs);

    // buckets -> tight CSR + per-row cnt/cur
    bin2csr_kernel<<<dim3(NB), dim3(512), 0, stream>>>(recs, bucketBase, cnt, cur, csr);

    const int gatherBlocks = (N_NODES + 7) / 8;       // 10000
    const int denseBlocks  = N_NODES / (16 * 4);      // 1250, exact

    for (int layer = 0; layer < 2; ++layer) {
        gather_kernel<<<dim3(gatherBlocks), dim3(512), 0, stream>>>(xc, agg, cnt, cur, csr);
        dense_mfma_kernel<<<dim3(denseBlocks, 2), dim3(256), 0, stream>>>(
            xc, agg, id_emb, Wbf, bfp, layer, flags);
    }

    const int n8 = N_NODES * DIM / 8;                 // 640000
    final_kernel<<<dim3((n8 + 255) / 256), dim3(256), 0, stream>>>(xc, d_out, flags, n8);
}

// Round 6
// 365.408 us; speedup vs baseline: 1.2941x; 1.1537x over previous
//
#include <hip/hip_runtime.h>
#include <hip/hip_bf16.h>

#define NUM_USER 50000
#define N_NODES  80000
#define DIM      64
#define NEG_SLOPE 0.01f

// bucket geometry: 256 rows per bucket, fixed capacity (no count pass)
#define NB 313               // ceil(80000/256)
#define BSHIFT 8
#define RMASK 255
#define CSHIFT 17
#define CMASK 0x1FFFF
#define CAP 10240            // item buckets ~6.8K +- 81 -> ~42 sigma margin

typedef __attribute__((ext_vector_type(8))) short short8;   // 8 bf16 = 4 VGPRs
typedef __attribute__((ext_vector_type(4))) float f32x4;    // MFMA 16x16 accumulator

typedef unsigned short XT;   // state dtype: bf16

__device__ __forceinline__ float leaky(float v) {
    return v > 0.0f ? v : v * NEG_SLOPE;
}

// flags[0]: edge_index is int64 (else int32)
// flags[1]: float inputs are bf16 (else fp32)
__device__ __forceinline__ int load_idx(const void* ei, int is64, long long pos) {
    if (is64) return (int)((const long long*)ei)[pos];
    return ((const int*)ei)[pos];
}
__device__ __forceinline__ float load_f(const void* p, int isbf16, size_t i) {
    if (isbf16) return __bfloat162float(((const __hip_bfloat16*)p)[i]);
    return ((const float*)p)[i];
}

__device__ __forceinline__ unsigned short f2bf(float f) {
    unsigned u = __float_as_uint(f);
    u += 0x7fffu + ((u >> 16) & 1u);   // RNE
    return (unsigned short)(u >> 16);
}

__device__ __forceinline__ void acc8(float* a, uint4 r) {
    a[0] += __uint_as_float(r.x << 16);
    a[1] += __uint_as_float(r.x & 0xffff0000u);
    a[2] += __uint_as_float(r.y << 16);
    a[3] += __uint_as_float(r.y & 0xffff0000u);
    a[4] += __uint_as_float(r.z << 16);
    a[5] += __uint_as_float(r.z & 0xffff0000u);
    a[6] += __uint_as_float(r.w << 16);
    a[7] += __uint_as_float(r.w & 0xffff0000u);
}

// ---------- detect (wave-parallel) + zero bucket cursors ----------
__global__ void detect_kernel(const unsigned int* __restrict__ feat_words,
                              const int* __restrict__ ei_words,
                              int* __restrict__ flags,
                              int* __restrict__ bucketCur) {
    int lane = threadIdx.x & 63;
    for (int i = lane; i < 320; i += 64) bucketCur[i] = 0;
    int orv = 0;
    for (int i = lane * 2 + 1; i < 1024; i += 128) orv |= ei_words[i];
    int hits = 0;
    for (int i = lane; i < 256; i += 64) {
        unsigned e = (feat_words[i] >> 7) & 0xFF;
        hits += (e == 126 || e == 127) ? 1 : 0;
    }
    #pragma unroll
    for (int d = 32; d > 0; d >>= 1) {
        orv  |= __shfl_xor(orv, d, 64);
        hits += __shfl_xor(hits, d, 64);
    }
    if (lane == 0 && blockIdx.x == 0) {
        flags[0] = (orv == 0) ? 1 : 0;
        flags[1] = (hits > 64) ? 1 : 0;
    }
}

// ---------- megafuse: binplace + init_x + W/b pack (three block ranges) ----------
__global__ __launch_bounds__(256) void megafuse_kernel(
        const void* __restrict__ ei, int E, int binBlocks, int initBlocks,
        const int* __restrict__ flags,
        int* __restrict__ bucketCur, unsigned int* __restrict__ recs,
        const void* __restrict__ vp, const void* __restrict__ tp,
        const void* __restrict__ vf, const void* __restrict__ tf,
        XT* __restrict__ xc,
        const void* __restrict__ vW, const void* __restrict__ tW,
        const void* __restrict__ vb, const void* __restrict__ tb,
        unsigned short* __restrict__ Wbf, float* __restrict__ bfp) {
    if ((int)blockIdx.x < binBlocks) {
        // ---- edges -> fixed-cap bucket records (block-aggregated cursors)
        __shared__ int bloc[320];
        __shared__ int bres[320];
        int tid = threadIdx.x;
        for (int i = tid; i < 320; i += 256) bloc[i] = 0;
        __syncthreads();
        int is64 = flags[0];
        long long base = (long long)blockIdx.x * 2048;
        int bb[8], cc[8], lp[8], rl[8];
        #pragma unroll
        for (int it = 0; it < 8; ++it) {
            bb[it] = -1;
            long long e = base + it * 256 + tid;
            if (e < E) {
                int r = load_idx(ei, is64, e);
                int c = load_idx(ei, is64, (long long)E + e);
                if ((unsigned)r < N_NODES && (unsigned)c < N_NODES) {
                    int b = r >> BSHIFT;
                    bb[it] = b;
                    cc[it] = c;
                    rl[it] = r & RMASK;
                    lp[it] = atomicAdd(&bloc[b], 1);
                }
            }
        }
        __syncthreads();
        for (int i = tid; i < NB; i += 256) {
            int v = bloc[i];
            bres[i] = v ? atomicAdd(&bucketCur[i], v) : 0;
        }
        __syncthreads();
        #pragma unroll
        for (int it = 0; it < 8; ++it) {
            if (bb[it] >= 0) {
                int pos = bres[bb[it]] + lp[it];
                if (pos < CAP)
                    recs[(size_t)bb[it] * CAP + pos] =
                        ((unsigned)rl[it] << CSHIFT) | (unsigned)cc[it];
            }
        }
    } else if ((int)blockIdx.x < binBlocks + initBlocks) {
        // ---- init_x: L2-normalize [pref|feat] rows -> bf16 state
        int n = (blockIdx.x - binBlocks) * 4 + (threadIdx.x >> 6);
        if (n >= N_NODES) return;
        int lane = threadIdx.x & 63;
        int isb = flags[1];
        float a, b;
        if (n < NUM_USER) {
            a = load_f(vp, isb, (size_t)n * DIM + lane);
            b = load_f(tp, isb, (size_t)n * DIM + lane);
        } else {
            a = load_f(vf, isb, (size_t)(n - NUM_USER) * DIM + lane);
            b = load_f(tf, isb, (size_t)(n - NUM_USER) * DIM + lane);
        }
        float sa = a * a, sb = b * b;
        #pragma unroll
        for (int d = 32; d > 0; d >>= 1) {
            sa += __shfl_xor(sa, d, 64);
            sb += __shfl_xor(sb, d, 64);
        }
        float ra = 1.0f / fmaxf(sqrtf(sa), 1e-12f);
        float rb = 1.0f / fmaxf(sqrtf(sb), 1e-12f);
        xc[(size_t)n * 128 + lane]      = f2bf(a * ra);
        xc[(size_t)n * 128 + 64 + lane] = f2bf(b * rb);
    } else {
        // ---- W/b pack
        int isb = flags[1];
        int j = (blockIdx.x - binBlocks - initBlocks) * 256 + threadIdx.x;
        if (j < 2 * 24576) {
            int tw = j / 24576, r = j % 24576;
            Wbf[j] = f2bf(load_f(tw ? tW : vW, isb, r));
        } else if (j < 2 * 24576 + 2 * 384) {
            int i2 = j - 2 * 24576;
            int tw = i2 / 384, r = i2 % 384;
            bfp[i2] = load_f(tw ? tb : vb, isb, r);
        }
    }
}

// ---------- bin2csr: one block per bucket (padded layout, base = b*CAP) ----------
__global__ __launch_bounds__(512) void bin2csr_kernel(
        const unsigned int* __restrict__ recs,
        const int* __restrict__ bucketCur,
        int* __restrict__ cnt, int* __restrict__ cur,
        int* __restrict__ csr) {
    __shared__ int rcnt[256];
    __shared__ int sc[256];
    __shared__ int lcur[256];
    int b = blockIdx.x;
    int t = threadIdx.x;
    int base = b * CAP;
    int count = bucketCur[b];
    if (count > CAP) count = CAP;

    if (t < 256) { rcnt[t] = 0; lcur[t] = 0; }
    __syncthreads();
    for (int i = t; i < count; i += 512) {
        unsigned rec = recs[(size_t)base + i];
        atomicAdd(&rcnt[rec >> CSHIFT], 1);
    }
    __syncthreads();
    int v = (t < 256) ? rcnt[t] : 0;
    if (t < 256) sc[t] = v;
    __syncthreads();
    for (int d = 1; d < 256; d <<= 1) {
        int x = 0;
        if (t < 256) { x = sc[t]; if (t >= d) x += sc[t - d]; }
        __syncthreads();
        if (t < 256) sc[t] = x;
        __syncthreads();
    }
    if (t < 256) {
        int row = (b << BSHIFT) + t;
        if (row < N_NODES) {
            cnt[row] = v;
            cur[row] = base + sc[t];   // row end; gather recovers start = cur - cnt
        }
    }
    __syncthreads();
    for (int i = t; i < count; i += 512) {
        unsigned rec = recs[(size_t)base + i];
        int rloc = rec >> CSHIFT;
        int c = rec & CMASK;
        int pos = base + (sc[rloc] - rcnt[rloc]) + atomicAdd(&lcur[rloc], 1);
        csr[pos] = c;
    }
}

// ---------- gather: agg[n] = mean over CSR neighbors (R3-proven variant) ----------
// 8 streams/wave: 8 lanes cover a 128B half-row (uint4/lane); group g8 = gg*2+h
// handles neighbors jj = gg (mod 4), half h; unroll-2 per stream.
__global__ __launch_bounds__(512) void gather_kernel(
        const XT* __restrict__ xc, XT* __restrict__ agg,
        const int* __restrict__ cnt, const int* __restrict__ cur,
        const int* __restrict__ csr) {
    int n = blockIdx.x * 8 + (threadIdx.x >> 6);
    if (n >= N_NODES) return;
    int lane = threadIdx.x & 63;
    int g8 = lane >> 3;      // 0..7
    int s  = lane & 7;       // 0..7
    int gg = g8 >> 1;        // 0..3: neighbor stride class
    int h  = g8 & 1;         // 0/1: row half

    int d = cnt[n];
    int base = cur[n] - d;   // row start in padded CSR
    const int* nb = csr + base;
    const XT* xh = xc + h * 64;

    float acc[8];
    #pragma unroll
    for (int f = 0; f < 8; ++f) acc[f] = 0.f;

    int jj = gg;
    for (; jj + 4 < d; jj += 8) {
        int c0 = nb[jj];
        int c1 = nb[jj + 4];
        uint4 r0 = ((const uint4*)(xh + (size_t)c0 * 128))[s];
        uint4 r1 = ((const uint4*)(xh + (size_t)c1 * 128))[s];
        acc8(acc, r0);
        acc8(acc, r1);
    }
    if (jj < d) {
        int c0 = nb[jj];
        uint4 r0 = ((const uint4*)(xh + (size_t)c0 * 128))[s];
        acc8(acc, r0);
    }

    // reduce across gg (lanes differing in bits 4 and 5; same h,s)
    #pragma unroll
    for (int dd = 16; dd < 64; dd <<= 1) {
        #pragma unroll
        for (int f = 0; f < 8; ++f) acc[f] += __shfl_xor(acc[f], dd, 64);
    }

    float invd = (d > 0) ? 1.0f / (float)d : 0.0f;
    if (g8 < 2) {   // gg == 0 lanes; h = g8 selects the half to write
        uint4 w;
        w.x = (unsigned)f2bf(acc[0] * invd) | ((unsigned)f2bf(acc[1] * invd) << 16);
        w.y = (unsigned)f2bf(acc[2] * invd) | ((unsigned)f2bf(acc[3] * invd) << 16);
        w.z = (unsigned)f2bf(acc[4] * invd) | ((unsigned)f2bf(acc[5] * invd) << 16);
        w.w = (unsigned)f2bf(acc[6] * invd) | ((unsigned)f2bf(acc[7] * invd) << 16);
        ((uint4*)(agg + (size_t)n * 128 + h * 64))[s] = w;
    }
}

// ---------- dense via MFMA 16x16x32 bf16, both towers per block ----------
// id_emb loaded ONCE (shared by towers). In-place xc update is safe: each
// block reads only its own 16-node rows (both towers) before its deferred
// writes. At last layer, writes (x_v+x_t)/2 straight to out (final_kernel
// folded in; layer-1 xc round-trip eliminated).
__global__ __launch_bounds__(256) void dense_mfma_kernel(
        XT* __restrict__ xc, const XT* __restrict__ agg,
        void* __restrict__ out, int last,
        const void* __restrict__ id_emb,
        const unsigned short* __restrict__ Wbf, const float* __restrict__ bfp,
        int layer, const int* __restrict__ flags) {
    __shared__ unsigned short hts[4][16 * 72];
    int wave = threadIdx.x >> 6, lane = threadIdx.x & 63;
    int quad = lane >> 4, l16 = lane & 15;
    int isb = flags[1];
    int n0 = (blockIdx.x * 4 + wave) * 16;
    unsigned short* ht = hts[wave];

    float xres[2][16];
    float idv[16];

    #pragma unroll
    for (int tw = 0; tw < 2; ++tw) {
        int toff = tw * 64;
        const unsigned short* Wm = Wbf + (size_t)((tw * 2 + layer) * 3) * 4096;
        const float* bb = bfp + (tw * 2 + layer) * 192;
        size_t arow = (size_t)(n0 + l16) * 128 + toff + quad * 8;

        short8 a0, a1;
        f32x4 accP[4];

        // M1: P = leaky(x @ W1^T + b1), in registers
        a0 = *(const short8*)(xc + arow);
        a1 = *(const short8*)(xc + arow + 32);
        #pragma unroll
        for (int t = 0; t < 4; ++t) {
            f32x4 c = {0.f, 0.f, 0.f, 0.f};
            short8 b0 = *(const short8*)(Wm + 4096 + (16 * t + l16) * 64 + quad * 8);
            short8 b1 = *(const short8*)(Wm + 4096 + (16 * t + l16) * 64 + 32 + quad * 8);
            c = __builtin_amdgcn_mfma_f32_16x16x32_bf16(a0, b0, c, 0, 0, 0);
            c = __builtin_amdgcn_mfma_f32_16x16x32_bf16(a1, b1, c, 0, 0, 0);
            float bias = bb[64 + 16 * t + l16];
            #pragma unroll
            for (int r = 0; r < 4; ++r) accP[t][r] = leaky(c[r] + bias);
        }

        // M0: h = leaky(agg @ W0^T + b0) -> LDS (C-layout -> A-layout)
        a0 = *(const short8*)(agg + arow);
        a1 = *(const short8*)(agg + arow + 32);
        #pragma unroll
        for (int t = 0; t < 4; ++t) {
            f32x4 c = {0.f, 0.f, 0.f, 0.f};
            short8 b0 = *(const short8*)(Wm + (16 * t + l16) * 64 + quad * 8);
            short8 b1 = *(const short8*)(Wm + (16 * t + l16) * 64 + 32 + quad * 8);
            c = __builtin_amdgcn_mfma_f32_16x16x32_bf16(a0, b0, c, 0, 0, 0);
            c = __builtin_amdgcn_mfma_f32_16x16x32_bf16(a1, b1, c, 0, 0, 0);
            float bias = bb[16 * t + l16];
            #pragma unroll
            for (int r = 0; r < 4; ++r)
                ht[(quad * 4 + r) * 72 + 16 * t + l16] = f2bf(leaky(c[r] + bias));
        }
        // wave-private LDS, in-order per wave -> no barrier

        // M2: x = leaky(h @ W2^T + b2 + P + id)
        a0 = *(const short8*)(ht + l16 * 72 + quad * 8);
        a1 = *(const short8*)(ht + l16 * 72 + 32 + quad * 8);
        #pragma unroll
        for (int t = 0; t < 4; ++t) {
            f32x4 c = {0.f, 0.f, 0.f, 0.f};
            short8 b0 = *(const short8*)(Wm + 2 * 4096 + (16 * t + l16) * 64 + quad * 8);
            short8 b1 = *(const short8*)(Wm + 2 * 4096 + (16 * t + l16) * 64 + 32 + quad * 8);
            c = __builtin_amdgcn_mfma_f32_16x16x32_bf16(a0, b0, c, 0, 0, 0);
            c = __builtin_amdgcn_mfma_f32_16x16x32_bf16(a1, b1, c, 0, 0, 0);
            float bias = bb[128 + 16 * t + l16];
            #pragma unroll
            for (int r = 0; r < 4; ++r) {
                int node2 = n0 + quad * 4 + r;
                int j = 16 * t + l16;
                if (tw == 0)
                    idv[t * 4 + r] = load_f(id_emb, isb, (size_t)node2 * 64 + j);
                xres[tw][t * 4 + r] = leaky(c[r] + bias + accP[t][r] + idv[t * 4 + r]);
            }
        }
    }

    if (!last) {
        #pragma unroll
        for (int tw = 0; tw < 2; ++tw) {
            #pragma unroll
            for (int t = 0; t < 4; ++t) {
                #pragma unroll
                for (int r = 0; r < 4; ++r) {
                    int node2 = n0 + quad * 4 + r;
                    int j = 16 * t + l16;
                    xc[(size_t)node2 * 128 + tw * 64 + j] = f2bf(xres[tw][t * 4 + r]);
                }
            }
        }
    } else {
        #pragma unroll
        for (int t = 0; t < 4; ++t) {
            #pragma unroll
            for (int r = 0; r < 4; ++r) {
                int node2 = n0 + quad * 4 + r;
                int j = 16 * t + l16;
                float avg = (xres[0][t * 4 + r] + xres[1][t * 4 + r]) * 0.5f;
                if (isb) ((unsigned short*)out)[(size_t)node2 * 64 + j] = f2bf(avg);
                else     ((float*)out)[(size_t)node2 * 64 + j] = avg;
            }
        }
    }
}

extern "C" void kernel_launch(void* const* d_in, const int* in_sizes, int n_in,
                              void* d_out, int out_size, void* d_ws, size_t ws_size,
                              hipStream_t stream) {
    const void* v_feat = d_in[0];
    const void* t_feat = d_in[1];
    const void* id_emb = d_in[2];
    const void* v_pref = d_in[3];
    const void* t_pref = d_in[4];
    const void* v_W    = d_in[5];
    const void* v_b    = d_in[6];
    const void* t_W    = d_in[7];
    const void* t_b    = d_in[8];
    const void* ei     = d_in[9];

    const int E = in_sizes[9] / 2;   // 1,600,000
    char* ws = (char*)d_ws;

    size_t o = 0;
    int*            flags     = (int*)(ws + o);            o += 16;
    int*            cnt       = (int*)(ws + o);            o += 320000;
    int*            cur       = (int*)(ws + o);            o += 320000;
    int*            bucketCur = (int*)(ws + o);            o += 320 * 4;
    unsigned short* Wbf       = (unsigned short*)(ws + o); o += 2 * 24576 * 2;
    float*          bfp       = (float*)(ws + o);          o += 2 * 384 * 4;
    XT* xc  = (XT*)(ws + o); o += (size_t)N_NODES * 128 * sizeof(XT);
    XT* agg = (XT*)(ws + o); o += (size_t)N_NODES * 128 * sizeof(XT);
    unsigned int* recs = (unsigned int*)(ws + o); o += (size_t)NB * CAP * 4;
    int* csr = (int*)(ws + o);                    // padded: NB*CAP*4 = 12.8 MB

    detect_kernel<<<dim3(1), dim3(64), 0, stream>>>(
        (const unsigned int*)v_feat, (const int*)ei, flags, bucketCur);

    // fused binplace + init_x + W/b pack
    const int binBlocks  = (E + 2047) / 2048;         // 782
    const int initBlocks = (N_NODES + 3) / 4;         // 20000
    const int packBlocks = (2 * 24576 + 2 * 384 + 255) / 256;
    megafuse_kernel<<<dim3(binBlocks + initBlocks + packBlocks), dim3(256), 0, stream>>>(
        ei, E, binBlocks, initBlocks, flags, bucketCur, recs,
        v_pref, t_pref, v_feat, t_feat, xc,
        v_W, t_W, v_b, t_b, Wbf, bfp);

    // buckets -> padded CSR + per-row cnt/cur
    bin2csr_kernel<<<dim3(NB), dim3(512), 0, stream>>>(recs, bucketCur, cnt, cur, csr);

    const int gatherBlocks = (N_NODES + 7) / 8;       // 10000
    const int denseBlocks  = N_NODES / (16 * 4);      // 1250, exact

    // layer 0 (in-place xc update), layer 1 (writes averaged output directly)
    gather_kernel<<<dim3(gatherBlocks), dim3(512), 0, stream>>>(xc, agg, cnt, cur, csr);
    dense_mfma_kernel<<<dim3(denseBlocks), dim3(256), 0, stream>>>(
        xc, agg, d_out, 0, id_emb, Wbf, bfp, 0, flags);
    gather_kernel<<<dim3(gatherBlocks), dim3(512), 0, stream>>>(xc, agg, cnt, cur, csr);
    dense_mfma_kernel<<<dim3(denseBlocks), dim3(256), 0, stream>>>(
        xc, agg, d_out, 1, id_emb, Wbf, bfp, 1, flags);
}